// Round 5
// baseline (2354.348 us; speedup 1.0000x reference)
//
#include <hip/hip_runtime.h>
#include <math.h>

#define T_STEPS 512
#define B_SZ    128
#define I_SZ    256
#define H_SZ    512
#define HX_SZ   768
#define NG      2048      // 4*H gate-columns, packed n = jh*4 + gate
#define KB_H    16        // k-instructions covering h part (512/32)
#define KB_X    8         // k-instructions covering x part (256/32)
#define KB_TOT  24        // total k-instructions (768/32)
#define W_ELEMS (HX_SZ * NG)   // 1,572,864 per pack
#define NWG     256
#define BH      (B_SZ * H_SZ)
#define BI      (B_SZ * I_SZ)

typedef __attribute__((ext_vector_type(8))) short bf16x8;   // MFMA A/B frag (4 VGPRs)
typedef __attribute__((ext_vector_type(4))) short bf16x4;   // 8B LDS store
typedef __attribute__((ext_vector_type(4))) float f32x4;    // MFMA C/D frag
typedef __attribute__((ext_vector_type(4))) unsigned int u32x4;

__device__ __forceinline__ unsigned short f2bf_rne(float f) {
    unsigned u = __builtin_bit_cast(unsigned, f);
    unsigned r = u + 0x7fffu + ((u >> 16) & 1u);
    return (unsigned short)(r >> 16);
}
__device__ __forceinline__ float bf2f(unsigned short h) {
    unsigned u = ((unsigned)h) << 16;
    return __builtin_bit_cast(float, u);
}
__device__ __forceinline__ float fast_tanh(float x) {
    x = fminf(15.f, fmaxf(-15.f, x));
    const float e = __expf(2.f * x);
    return (e - 1.f) / (e + 1.f);
}

// ---- Pack W{f,i,c,o}[768][512] into MFMA-B-fragment order, bf16 hi + lo ----
__global__ __launch_bounds__(256) void repack_frag(
    const float* __restrict__ Wf, const float* __restrict__ Wi,
    const float* __restrict__ Wc, const float* __restrict__ Wo,
    unsigned short* __restrict__ Whi, unsigned short* __restrict__ Wlo)
{
    int id = blockIdx.x * 256 + threadIdx.x;           // [0, 1572864)
    int j    = id & 7;
    int lane = (id >> 3) & 63;
    int fkb  = (id >> 9);
    int kb   = fkb % KB_TOT;
    int ng   = fkb / KB_TOT;
    int n = ng * 16 + (lane & 15);
    int k = kb * 32 + (lane >> 4) * 8 + j;
    int g  = n & 3;
    int jh = n >> 2;
    const float* Ws = (g == 0) ? Wf : (g == 1) ? Wi : (g == 2) ? Wc : Wo;
    float w = Ws[k * H_SZ + jh];
    unsigned short wh = f2bf_rne(w);
    unsigned short wl = f2bf_rne(w - bf2f(wh));
    Whi[id] = wh;
    Wlo[id] = wl;
}

__global__ __launch_bounds__(256) void pack_bias(
    const float* __restrict__ bf, const float* __restrict__ bi,
    const float* __restrict__ bc, const float* __restrict__ bo,
    float* __restrict__ bpk)
{
    int c = blockIdx.x * 256 + threadIdx.x;   // [0, 2048)
    int jh = c >> 2, g = c & 3;
    const float* bs = (g == 0) ? bf : (g == 1) ? bi : (g == 2) ? bc : bo;
    bpk[c] = bs[jh];
}

// Init packed-h buffers with parity-mismatched epochs (buf0: ep=1, buf1: ep=0)
// via sc0sc1 stores (MALL-visible; consumers read with sc1 and bypass L2).
// buf0 is read at odd t expecting ep in {0,2}; buf1 at even t expecting {1,3}.
__global__ __launch_bounds__(256) void init_h(unsigned int* __restrict__ hpk)
{
    int i = blockIdx.x * 256 + threadIdx.x;   // [0, 2*BH)
    const unsigned v = (i < BH) ? 1u : 0u;
    const unsigned int* p = hpk + i;
    asm volatile("global_store_dword %0, %1, off sc0 sc1"
                 :: "v"(p), "v"(v) : "memory");
}

// ---- Persistent LSTM: all 512 timesteps in one launch ----
// 256 WGs x 256 thr, 1 WG/CU. Weights pinned in AGPR/VGPR via asm keep-alive.
// 8 sync groups (one per 16-row b-tile). h exchange is SELF-VALIDATING:
// each h element is one packed dword (hi<<16 | lo&~3 | epoch2) stored sc0sc1.
// No flags, no release drain, no separate poll: the consumer loads the data
// slice and checks the 2-bit epoch of every word (stale value can only be
// h(t-2), epoch differs by 2 mod 4). A speculative sample is issued right
// after our own release so in lockstep it usually validates first try.
__global__ __launch_bounds__(256, 1) void lstm_persist(
    const float* __restrict__ x_all,           // [T][B][I] fp32
    const unsigned short* __restrict__ Whi,    // frag-packed bf16 hi
    const unsigned short* __restrict__ Wlo,    // frag-packed bf16 lo
    const float* __restrict__ bpk,             // [2048] packed bias
    float* __restrict__ out,                   // [T][B][H] fp32
    unsigned int* __restrict__ hpk)            // [2][B][H] packed hi|lo|epoch
{
    __shared__ __align__(16) unsigned short sh_hi[16 * 512];
    __shared__ __align__(16) unsigned short sh_lo[16 * 512];
    __shared__ __align__(16) unsigned short sx_hi[16 * 256];
    __shared__ __align__(16) unsigned short sx_lo[16 * 256];
    __shared__ float preact[16][64];

    const int tid  = threadIdx.x;
    const int lane = tid & 63;
    const int wv   = tid >> 6;
    const int w    = blockIdx.x;
    const int xcd  = w & 7;
    const int q    = w >> 3;
    const int bt   = q & 7;
    const int ngg  = xcd * 4 + (q >> 3);
    const int ng   = ngg * 4 + wv;
    const int b0   = bt * 16;
    const int mrow = lane & 15;
    const int quad = lane >> 4;

    // ---- load weight fragments once; pin (anti-remat keep-alive) ----
    bf16x8 wh[KB_TOT], wl[KB_TOT];
    {
        const bf16x8* __restrict__ Wh8 = (const bf16x8*)Whi;
        const bf16x8* __restrict__ Wl8 = (const bf16x8*)Wlo;
        const int wbase = ng * KB_TOT * 64 + lane;
        #pragma unroll
        for (int kb = 0; kb < KB_TOT; ++kb) {
            wh[kb] = Wh8[wbase + kb * 64];
            wl[kb] = Wl8[wbase + kb * 64];
        }
    }
    #pragma unroll
    for (int kb = 0; kb < KB_TOT; ++kb) {
        asm volatile("" : "+v"(wh[kb]));
        asm volatile("" : "+v"(wl[kb]));
    }

    // ---- pointwise role: thread -> (b_local, hidden_local); C stays in reg ----
    const int bl = tid >> 4;
    const int jl = tid & 15;
    const int pidx = (b0 + bl) * H_SZ + ngg * 16 + jl;
    const f32x4 bias = ((const f32x4*)bpk)[ngg * 16 + jl];
    float Creg = 0.f;

    // ---- staging offsets; XOR swizzle = ((row&15)<<3) shorts ----
    int hgo[4], xgo[4], hlds[4], xlds[4];
    #pragma unroll
    for (int r = 0; r < 4; ++r) {
        const int row = r * 4 + wv;
        hgo[r]  = (b0 + row) * H_SZ + lane * 8;          // packed-dword index
        hlds[r] = (row * 512 + lane * 8) ^ ((row & 15) << 3);
        xgo[r]  = (b0 + row) * I_SZ + lane * 4;          // 4 floats
        xlds[r] = (row * 256 + lane * 4) ^ ((row & 15) << 3);
    }
    const int hfr = mrow * 512 + quad * 8;   // A-frag read base (shorts)
    const int xfr = mrow * 256 + quad * 8;
    const int swz = (mrow & 15) << 3;

    // ---- prologue: prefetch x(0) ----
    f32x4 xpre[4];
    #pragma unroll
    for (int r = 0; r < 4; ++r)
        xpre[r] = *(const f32x4*)(x_all + xgo[r]);

    u32x4 smp[8];   // speculative h sample: 4 rows x 8 packed dwords/lane

    for (int t = 0; t < T_STEPS; ++t) {
        // ---- stage x(t): fp32 regs -> bf16 hi/lo in LDS ----
        #pragma unroll
        for (int r = 0; r < 4; ++r) {
            bf16x4 hv, lv;
            #pragma unroll
            for (int j = 0; j < 4; ++j) {
                const unsigned short hb = f2bf_rne(xpre[r][j]);
                hv[j] = (short)hb;
                lv[j] = (short)f2bf_rne(xpre[r][j] - bf2f(hb));
            }
            *(bf16x4*)&sx_hi[xlds[r]] = hv;
            *(bf16x4*)&sx_lo[xlds[r]] = lv;
        }
        __syncthreads();   // B1: sx ready

        // ---- prefetch x(t+1) (plain cached loads) ----
        if (t + 1 < T_STEPS) {
            const float* __restrict__ xn = x_all + (size_t)(t + 1) * BI;
            #pragma unroll
            for (int r = 0; r < 4; ++r)
                xpre[r] = *(const f32x4*)(xn + xgo[r]);
        }

        // ---- x-part MFMAs: 3 independent chains (overlap h sample flight) ----
        f32x4 a0 = {0.f, 0.f, 0.f, 0.f};
        f32x4 a1 = {0.f, 0.f, 0.f, 0.f};
        f32x4 a2 = {0.f, 0.f, 0.f, 0.f};
        #pragma unroll
        for (int kxb = 0; kxb < KB_X; ++kxb) {
            const int off = (xfr + kxb * 32) ^ swz;
            const bf16x8 xh = *(const bf16x8*)&sx_hi[off];
            const bf16x8 xl = *(const bf16x8*)&sx_lo[off];
            a0 = __builtin_amdgcn_mfma_f32_16x16x32_bf16(xh, wh[KB_H + kxb], a0, 0, 0, 0);
            a1 = __builtin_amdgcn_mfma_f32_16x16x32_bf16(xl, wh[KB_H + kxb], a1, 0, 0, 0);
            a2 = __builtin_amdgcn_mfma_f32_16x16x32_bf16(xh, wl[KB_H + kxb], a2, 0, 0, 0);
        }

        if (t > 0) {
            // ---- validate speculative sample; retry until all epochs match ----
            const unsigned ep = (unsigned)((t - 1) & 3);
            const unsigned int* __restrict__ hrd = hpk + ((t - 1) & 1) * BH;
            asm volatile("s_waitcnt vmcnt(0)" ::: "memory");
            __builtin_amdgcn_sched_barrier(0);
            const unsigned long long wd0 = __builtin_amdgcn_s_memrealtime();
            for (;;) {
                unsigned m = 0;
                #pragma unroll
                for (int i = 0; i < 8; ++i) {
                    m |= (smp[i][0] ^ ep); m |= (smp[i][1] ^ ep);
                    m |= (smp[i][2] ^ ep); m |= (smp[i][3] ^ ep);
                }
                if (__all((m & 3u) == 0u)) break;
                if (__builtin_amdgcn_s_memrealtime() - wd0 > 10000000ull) break;
                __builtin_amdgcn_s_sleep(1);
                #pragma unroll
                for (int r = 0; r < 4; ++r) {
                    asm volatile("global_load_dwordx4 %0, %1, off sc0 sc1"
                                 : "=v"(smp[2 * r]) : "v"(hrd + hgo[r]));
                    asm volatile("global_load_dwordx4 %0, %1, off sc0 sc1"
                                 : "=v"(smp[2 * r + 1]) : "v"(hrd + hgo[r] + 4));
                }
                asm volatile("s_waitcnt vmcnt(0)" ::: "memory");
                __builtin_amdgcn_sched_barrier(0);
            }

            // ---- unpack packed words -> sh_hi/sh_lo (swizzled) ----
            #pragma unroll
            for (int r = 0; r < 4; ++r) {
                const u32x4 pa = smp[2 * r];
                const u32x4 pb = smp[2 * r + 1];
                u32x4 hi, lo;
                hi[0] = (pa[0] >> 16) | (pa[1] & 0xffff0000u);
                hi[1] = (pa[2] >> 16) | (pa[3] & 0xffff0000u);
                hi[2] = (pb[0] >> 16) | (pb[1] & 0xffff0000u);
                hi[3] = (pb[2] >> 16) | (pb[3] & 0xffff0000u);
                lo[0] = (pa[0] & 0xffffu) | (pa[1] << 16);
                lo[1] = (pa[2] & 0xffffu) | (pa[3] << 16);
                lo[2] = (pb[0] & 0xffffu) | (pb[1] << 16);
                lo[3] = (pb[2] & 0xffffu) | (pb[3] << 16);
                *(u32x4*)&sh_hi[hlds[r]] = hi;
                *(u32x4*)&sh_lo[hlds[r]] = lo;
            }
            __syncthreads();   // B3: sh ready

            // ---- h-part MFMAs ----
            #pragma unroll
            for (int kb = 0; kb < KB_H; ++kb) {
                const int off = (hfr + kb * 32) ^ swz;
                const bf16x8 ah = *(const bf16x8*)&sh_hi[off];
                const bf16x8 al = *(const bf16x8*)&sh_lo[off];
                a0 = __builtin_amdgcn_mfma_f32_16x16x32_bf16(ah, wh[kb], a0, 0, 0, 0);
                a1 = __builtin_amdgcn_mfma_f32_16x16x32_bf16(al, wh[kb], a1, 0, 0, 0);
                a2 = __builtin_amdgcn_mfma_f32_16x16x32_bf16(ah, wl[kb], a2, 0, 0, 0);
            }
        }

        const f32x4 acc = a0 + a1 + a2;

        // ---- stage pre-activations (D: col=lane&15, row=quad*4+r) ----
        #pragma unroll
        for (int r = 0; r < 4; ++r)
            preact[quad * 4 + r][wv * 16 + mrow] = acc[r];
        __syncthreads();   // B4: preact ready

        // ---- pointwise ----
        const f32x4 pa = *(const f32x4*)&preact[bl][jl * 4];
        const float pf = pa[0] + bias[0];
        const float pi = pa[1] + bias[1];
        const float pc = pa[2] + bias[2];
        const float po = pa[3] + bias[3];
        const float fg = 1.f / (1.f + __expf(-pf));
        const float ig = 1.f / (1.f + __expf(-pi));
        const float cb = fast_tanh(pc);
        const float og = 1.f / (1.f + __expf(-po));
        const float Cn = fg * Creg + ig * cb;
        const float hn = og * fast_tanh(Cn);
        Creg = Cn;

        // ---- release: ONE self-validating packed sc0sc1 store (no drain!) ----
        const unsigned short hb16 = f2bf_rne(hn);
        const unsigned short lb16 = f2bf_rne(hn - bf2f(hb16));
        const unsigned wpk = ((unsigned)hb16 << 16) | ((unsigned)lb16 & 0xFFFCu)
                           | (unsigned)(t & 3);
        {
            const unsigned int* ph = hpk + (t & 1) * BH + pidx;
            asm volatile("global_store_dword %0, %1, off sc0 sc1"
                         :: "v"(ph), "v"(wpk) : "memory");
        }
        out[(size_t)t * BH + pidx] = hn;

        // ---- speculative sample of h(t) for next iteration ----
        if (t + 1 < T_STEPS) {
            const unsigned int* __restrict__ hnx = hpk + (t & 1) * BH;
            #pragma unroll
            for (int r = 0; r < 4; ++r) {
                asm volatile("global_load_dwordx4 %0, %1, off sc0 sc1"
                             : "=v"(smp[2 * r]) : "v"(hnx + hgo[r]));
                asm volatile("global_load_dwordx4 %0, %1, off sc0 sc1"
                             : "=v"(smp[2 * r + 1]) : "v"(hnx + hgo[r] + 4));
            }
        }
    }
}

extern "C" void kernel_launch(void* const* d_in, const int* in_sizes, int n_in,
                              void* d_out, int out_size, void* d_ws, size_t ws_size,
                              hipStream_t stream)
{
    const float* x  = (const float*)d_in[0];
    const float* Wf = (const float*)d_in[1];
    const float* bf = (const float*)d_in[2];
    const float* Wi = (const float*)d_in[3];
    const float* bi = (const float*)d_in[4];
    const float* Wc = (const float*)d_in[5];
    const float* bc = (const float*)d_in[6];
    const float* Wo = (const float*)d_in[7];
    const float* bo = (const float*)d_in[8];
    float* out = (float*)d_out;

    // ---- workspace layout (all 16B aligned) ----
    unsigned short* Whi = (unsigned short*)d_ws;          // 1,572,864 shorts
    unsigned short* Wlo = Whi + W_ELEMS;                  // 1,572,864 shorts
    float* bpk = (float*)(Wlo + W_ELEMS);                 // 2048 floats
    unsigned int* hpk = (unsigned int*)(bpk + NG);        // [2][BH] packed h

    repack_frag<<<W_ELEMS / 256, 256, 0, stream>>>(Wf, Wi, Wc, Wo, Whi, Wlo);
    pack_bias<<<NG / 256, 256, 0, stream>>>(bf, bi, bc, bo, bpk);
    init_h<<<2 * BH / 256, 256, 0, stream>>>(hpk);
    lstm_persist<<<NWG, 256, 0, stream>>>(x, Whi, Wlo, bpk, out, hpk);
}

// Round 6
// 1913.108 us; speedup vs baseline: 1.2306x; 1.2306x over previous
//
#include <hip/hip_runtime.h>
#include <math.h>

#define T_STEPS 512
#define B_SZ    128
#define I_SZ    256
#define H_SZ    512
#define HX_SZ   768
#define NG      2048      // 4*H gate-columns, packed n = jh*4 + gate
#define KB_H    16        // k-instructions covering h part (512/32)
#define KB_X    8         // k-instructions covering x part (256/32)
#define KB_TOT  24        // total k-instructions (768/32)
#define W_ELEMS (HX_SZ * NG)   // 1,572,864 per pack
#define NWG     256
#define BH      (B_SZ * H_SZ)
#define BI      (B_SZ * I_SZ)

typedef __attribute__((ext_vector_type(8))) short bf16x8;   // MFMA A/B frag (4 VGPRs)
typedef __attribute__((ext_vector_type(4))) short bf16x4;   // 8B LDS store
typedef __attribute__((ext_vector_type(4))) float f32x4;    // MFMA C/D frag
typedef __attribute__((ext_vector_type(4))) unsigned int u32x4;

__device__ __forceinline__ unsigned short f2bf_rne(float f) {
    unsigned u = __builtin_bit_cast(unsigned, f);
    unsigned r = u + 0x7fffu + ((u >> 16) & 1u);
    return (unsigned short)(r >> 16);
}
__device__ __forceinline__ float bf2f(unsigned short h) {
    unsigned u = ((unsigned)h) << 16;
    return __builtin_bit_cast(float, u);
}
__device__ __forceinline__ float fast_tanh(float x) {
    x = fminf(15.f, fmaxf(-15.f, x));
    const float e = __expf(2.f * x);
    return (e - 1.f) / (e + 1.f);
}

// ---- Pack W{f,i,c,o}[768][512] into MFMA-B-fragment order, bf16 hi + lo ----
__global__ __launch_bounds__(256) void repack_frag(
    const float* __restrict__ Wf, const float* __restrict__ Wi,
    const float* __restrict__ Wc, const float* __restrict__ Wo,
    unsigned short* __restrict__ Whi, unsigned short* __restrict__ Wlo)
{
    int id = blockIdx.x * 256 + threadIdx.x;           // [0, 1572864)
    int j    = id & 7;
    int lane = (id >> 3) & 63;
    int fkb  = (id >> 9);
    int kb   = fkb % KB_TOT;
    int ng   = fkb / KB_TOT;
    int n = ng * 16 + (lane & 15);
    int k = kb * 32 + (lane >> 4) * 8 + j;
    int g  = n & 3;
    int jh = n >> 2;
    const float* Ws = (g == 0) ? Wf : (g == 1) ? Wi : (g == 2) ? Wc : Wo;
    float w = Ws[k * H_SZ + jh];
    unsigned short wh = f2bf_rne(w);
    unsigned short wl = f2bf_rne(w - bf2f(wh));
    Whi[id] = wh;
    Wlo[id] = wl;
}

__global__ __launch_bounds__(256) void pack_bias(
    const float* __restrict__ bf, const float* __restrict__ bi,
    const float* __restrict__ bc, const float* __restrict__ bo,
    float* __restrict__ bpk)
{
    int c = blockIdx.x * 256 + threadIdx.x;   // [0, 2048)
    int jh = c >> 2, g = c & 3;
    const float* bs = (g == 0) ? bf : (g == 1) ? bi : (g == 2) ? bc : bo;
    bpk[c] = bs[jh];
}

// Init packed-h buffers with parity-mismatched epochs (buf0: ep=1, buf1: ep=0)
// via sc0sc1 stores. buf0 is read at odd t expecting ep in {0,2}; buf1 at
// even t expecting {1,3} -> stale cross-launch values never validate.
__global__ __launch_bounds__(256) void init_h(unsigned int* __restrict__ hpk)
{
    int i = blockIdx.x * 256 + threadIdx.x;   // [0, 2*BH)
    const unsigned v = (i < BH) ? 1u : 0u;
    const unsigned int* p = hpk + i;
    asm volatile("global_store_dword %0, %1, off sc0 sc1"
                 :: "v"(p), "v"(v) : "memory");
}

// ---- Persistent LSTM: all 512 timesteps in one launch ----
// 256 WGs x 256 thr, 1 WG/CU. Weights pinned in AGPR/VGPR via asm keep-alive.
// 8 sync groups (one per 16-row b-tile). h exchange is SELF-VALIDATING: each
// h element is one packed dword (hi<<16 | lo&~3 | epoch2) stored sc0sc1 with
// NO producer drain and NO flags. Correctness: consumer at step t has
// consumed all peers' h(t-2), so peers completed t-3; the read buffer can
// only hold h(t-1) (epoch match) or h(t-3) (epoch differs by 2 mod 4 ->
// retry); per-address coherence forbids older values. Sampling schedule
// (the round-5 fix): the sample is issued right AFTER B1 of the consuming
// step -- when lockstep peers have just released -- and its RT hides under
// the x-part MFMAs; the successful poll iteration RETURNS the data, so
// there is no separate h-load leg at all.
__global__ __launch_bounds__(256, 1) void lstm_persist(
    const float* __restrict__ x_all,           // [T][B][I] fp32
    const unsigned short* __restrict__ Whi,    // frag-packed bf16 hi
    const unsigned short* __restrict__ Wlo,    // frag-packed bf16 lo
    const float* __restrict__ bpk,             // [2048] packed bias
    float* __restrict__ out,                   // [T][B][H] fp32
    unsigned int* __restrict__ hpk)            // [2][B][H] packed hi|lo|epoch
{
    __shared__ __align__(16) unsigned short sh_hi[16 * 512];
    __shared__ __align__(16) unsigned short sh_lo[16 * 512];
    __shared__ __align__(16) unsigned short sx_hi[16 * 256];
    __shared__ __align__(16) unsigned short sx_lo[16 * 256];
    __shared__ float preact[16][64];

    const int tid  = threadIdx.x;
    const int lane = tid & 63;
    const int wv   = tid >> 6;
    const int w    = blockIdx.x;
    const int xcd  = w & 7;
    const int q    = w >> 3;
    const int bt   = q & 7;
    const int ngg  = xcd * 4 + (q >> 3);
    const int ng   = ngg * 4 + wv;
    const int b0   = bt * 16;
    const int mrow = lane & 15;
    const int quad = lane >> 4;

    // ---- load weight fragments once; pin (anti-remat keep-alive) ----
    bf16x8 wh[KB_TOT], wl[KB_TOT];
    {
        const bf16x8* __restrict__ Wh8 = (const bf16x8*)Whi;
        const bf16x8* __restrict__ Wl8 = (const bf16x8*)Wlo;
        const int wbase = ng * KB_TOT * 64 + lane;
        #pragma unroll
        for (int kb = 0; kb < KB_TOT; ++kb) {
            wh[kb] = Wh8[wbase + kb * 64];
            wl[kb] = Wl8[wbase + kb * 64];
        }
    }
    #pragma unroll
    for (int kb = 0; kb < KB_TOT; ++kb) {
        asm volatile("" : "+v"(wh[kb]));
        asm volatile("" : "+v"(wl[kb]));
    }

    // ---- pointwise role: thread -> (b_local, hidden_local); C stays in reg ----
    const int bl = tid >> 4;
    const int jl = tid & 15;
    const int pidx = (b0 + bl) * H_SZ + ngg * 16 + jl;
    const f32x4 bias = ((const f32x4*)bpk)[ngg * 16 + jl];
    float Creg = 0.f;

    // ---- staging offsets; XOR swizzle = ((row&15)<<3) shorts ----
    int hgo[4], xgo[4], hlds[4], xlds[4];
    #pragma unroll
    for (int r = 0; r < 4; ++r) {
        const int row = r * 4 + wv;
        hgo[r]  = (b0 + row) * H_SZ + lane * 8;          // packed-dword index
        hlds[r] = (row * 512 + lane * 8) ^ ((row & 15) << 3);
        xgo[r]  = (b0 + row) * I_SZ + lane * 4;          // 4 floats
        xlds[r] = (row * 256 + lane * 4) ^ ((row & 15) << 3);
    }
    const int hfr = mrow * 512 + quad * 8;   // A-frag read base (shorts)
    const int xfr = mrow * 256 + quad * 8;
    const int swz = (mrow & 15) << 3;

    // ---- prologue: prefetch x(0) ----
    f32x4 xpre[4];
    #pragma unroll
    for (int r = 0; r < 4; ++r)
        xpre[r] = *(const f32x4*)(x_all + xgo[r]);

    u32x4 smp[8];   // h sample: 4 rows x 8 packed dwords/lane

    for (int t = 0; t < T_STEPS; ++t) {
        // ---- stage x(t): fp32 regs -> bf16 hi/lo in LDS ----
        #pragma unroll
        for (int r = 0; r < 4; ++r) {
            bf16x4 hv, lv;
            #pragma unroll
            for (int j = 0; j < 4; ++j) {
                const unsigned short hb = f2bf_rne(xpre[r][j]);
                hv[j] = (short)hb;
                lv[j] = (short)f2bf_rne(xpre[r][j] - bf2f(hb));
            }
            *(bf16x4*)&sx_hi[xlds[r]] = hv;
            *(bf16x4*)&sx_lo[xlds[r]] = lv;
        }
        __syncthreads();   // B1: sx ready

        // ---- issue h(t-1) sample NOW (peers just released); RT hides under
        //      the x-MFMAs below ----
        const unsigned ep = (unsigned)((t - 1) & 3);
        const unsigned int* __restrict__ hrd = hpk + ((t - 1) & 1) * BH;
        if (t > 0) {
            #pragma unroll
            for (int r = 0; r < 4; ++r) {
                asm volatile("global_load_dwordx4 %0, %1, off sc0 sc1"
                             : "=v"(smp[2 * r]) : "v"(hrd + hgo[r]));
                asm volatile("global_load_dwordx4 %0, %1, off sc0 sc1"
                             : "=v"(smp[2 * r + 1]) : "v"(hrd + hgo[r] + 4));
            }
            __builtin_amdgcn_sched_barrier(0);   // keep x-MFMAs below the issue
        }

        // ---- prefetch x(t+1) (plain cached loads) ----
        if (t + 1 < T_STEPS) {
            const float* __restrict__ xn = x_all + (size_t)(t + 1) * BI;
            #pragma unroll
            for (int r = 0; r < 4; ++r)
                xpre[r] = *(const f32x4*)(xn + xgo[r]);
        }

        // ---- x-part MFMAs: 3 independent chains (hide sample RT) ----
        f32x4 a0 = {0.f, 0.f, 0.f, 0.f};
        f32x4 a1 = {0.f, 0.f, 0.f, 0.f};
        f32x4 a2 = {0.f, 0.f, 0.f, 0.f};
        f32x4 b0c = {0.f, 0.f, 0.f, 0.f};
        f32x4 b1c = {0.f, 0.f, 0.f, 0.f};
        f32x4 b2c = {0.f, 0.f, 0.f, 0.f};
        #pragma unroll
        for (int kxb = 0; kxb < KB_X; ++kxb) {
            const int off = (xfr + kxb * 32) ^ swz;
            const bf16x8 xh = *(const bf16x8*)&sx_hi[off];
            const bf16x8 xl = *(const bf16x8*)&sx_lo[off];
            a0 = __builtin_amdgcn_mfma_f32_16x16x32_bf16(xh, wh[KB_H + kxb], a0, 0, 0, 0);
            a1 = __builtin_amdgcn_mfma_f32_16x16x32_bf16(xl, wh[KB_H + kxb], a1, 0, 0, 0);
            a2 = __builtin_amdgcn_mfma_f32_16x16x32_bf16(xh, wl[KB_H + kxb], a2, 0, 0, 0);
        }

        if (t > 0) {
            // ---- validate sample; on failure reload immediately ----
            asm volatile("s_waitcnt vmcnt(0)" ::: "memory");
            __builtin_amdgcn_sched_barrier(0);
            const unsigned long long wd0 = __builtin_amdgcn_s_memrealtime();
            for (;;) {
                unsigned m = 0;
                #pragma unroll
                for (int i = 0; i < 8; ++i) {
                    m |= (smp[i][0] ^ ep); m |= (smp[i][1] ^ ep);
                    m |= (smp[i][2] ^ ep); m |= (smp[i][3] ^ ep);
                }
                if (__all((m & 3u) == 0u)) break;
                // watchdog: ~100ms -> visible wrong answer, never a hang
                if (__builtin_amdgcn_s_memrealtime() - wd0 > 10000000ull) break;
                __builtin_amdgcn_s_sleep(1);
                #pragma unroll
                for (int r = 0; r < 4; ++r) {
                    asm volatile("global_load_dwordx4 %0, %1, off sc0 sc1"
                                 : "=v"(smp[2 * r]) : "v"(hrd + hgo[r]));
                    asm volatile("global_load_dwordx4 %0, %1, off sc0 sc1"
                                 : "=v"(smp[2 * r + 1]) : "v"(hrd + hgo[r] + 4));
                }
                asm volatile("s_waitcnt vmcnt(0)" ::: "memory");
                __builtin_amdgcn_sched_barrier(0);
            }

            // ---- unpack packed words -> sh_hi/sh_lo (swizzled) ----
            #pragma unroll
            for (int r = 0; r < 4; ++r) {
                const u32x4 pa = smp[2 * r];
                const u32x4 pb = smp[2 * r + 1];
                u32x4 hi, lo;
                hi[0] = (pa[0] >> 16) | (pa[1] & 0xffff0000u);
                hi[1] = (pa[2] >> 16) | (pa[3] & 0xffff0000u);
                hi[2] = (pb[0] >> 16) | (pb[1] & 0xffff0000u);
                hi[3] = (pb[2] >> 16) | (pb[3] & 0xffff0000u);
                lo[0] = (pa[0] & 0xffffu) | (pa[1] << 16);
                lo[1] = (pa[2] & 0xffffu) | (pa[3] << 16);
                lo[2] = (pb[0] & 0xffffu) | (pb[1] << 16);
                lo[3] = (pb[2] & 0xffffu) | (pb[3] << 16);
                *(u32x4*)&sh_hi[hlds[r]] = hi;
                *(u32x4*)&sh_lo[hlds[r]] = lo;
            }
            __syncthreads();   // B3: sh ready

            // ---- h-part MFMAs: first half on a-chains, second on b-chains ----
            #pragma unroll
            for (int kb = 0; kb < 8; ++kb) {
                const int off = (hfr + kb * 32) ^ swz;
                const bf16x8 ah = *(const bf16x8*)&sh_hi[off];
                const bf16x8 al = *(const bf16x8*)&sh_lo[off];
                a0 = __builtin_amdgcn_mfma_f32_16x16x32_bf16(ah, wh[kb], a0, 0, 0, 0);
                a1 = __builtin_amdgcn_mfma_f32_16x16x32_bf16(al, wh[kb], a1, 0, 0, 0);
                a2 = __builtin_amdgcn_mfma_f32_16x16x32_bf16(ah, wl[kb], a2, 0, 0, 0);
            }
            #pragma unroll
            for (int kb = 8; kb < KB_H; ++kb) {
                const int off = (hfr + kb * 32) ^ swz;
                const bf16x8 ah = *(const bf16x8*)&sh_hi[off];
                const bf16x8 al = *(const bf16x8*)&sh_lo[off];
                b0c = __builtin_amdgcn_mfma_f32_16x16x32_bf16(ah, wh[kb], b0c, 0, 0, 0);
                b1c = __builtin_amdgcn_mfma_f32_16x16x32_bf16(al, wh[kb], b1c, 0, 0, 0);
                b2c = __builtin_amdgcn_mfma_f32_16x16x32_bf16(ah, wl[kb], b2c, 0, 0, 0);
            }
        }

        const f32x4 acc = (a0 + a1) + (a2 + b0c) + (b1c + b2c);

        // ---- stage pre-activations (D: col=lane&15, row=quad*4+r) ----
        #pragma unroll
        for (int r = 0; r < 4; ++r)
            preact[quad * 4 + r][wv * 16 + mrow] = acc[r];
        __syncthreads();   // B4: preact ready

        // ---- pointwise ----
        const f32x4 pa = *(const f32x4*)&preact[bl][jl * 4];
        const float pf = pa[0] + bias[0];
        const float pi = pa[1] + bias[1];
        const float pc = pa[2] + bias[2];
        const float po = pa[3] + bias[3];
        const float fg = 1.f / (1.f + __expf(-pf));
        const float ig = 1.f / (1.f + __expf(-pi));
        const float cb = fast_tanh(pc);
        const float og = 1.f / (1.f + __expf(-po));
        const float Cn = fg * Creg + ig * cb;
        const float hn = og * fast_tanh(Cn);
        Creg = Cn;

        // ---- release: ONE self-validating packed sc0sc1 store (no drain) ----
        const unsigned short hb16 = f2bf_rne(hn);
        const unsigned short lb16 = f2bf_rne(hn - bf2f(hb16));
        const unsigned wpk = ((unsigned)hb16 << 16) | ((unsigned)lb16 & 0xFFFCu)
                           | (unsigned)(t & 3);
        {
            const unsigned int* ph = hpk + (t & 1) * BH + pidx;
            asm volatile("global_store_dword %0, %1, off sc0 sc1"
                         :: "v"(ph), "v"(wpk) : "memory");
        }
        out[(size_t)t * BH + pidx] = hn;   // off the release critical path
    }
}

extern "C" void kernel_launch(void* const* d_in, const int* in_sizes, int n_in,
                              void* d_out, int out_size, void* d_ws, size_t ws_size,
                              hipStream_t stream)
{
    const float* x  = (const float*)d_in[0];
    const float* Wf = (const float*)d_in[1];
    const float* bf = (const float*)d_in[2];
    const float* Wi = (const float*)d_in[3];
    const float* bi = (const float*)d_in[4];
    const float* Wc = (const float*)d_in[5];
    const float* bc = (const float*)d_in[6];
    const float* Wo = (const float*)d_in[7];
    const float* bo = (const float*)d_in[8];
    float* out = (float*)d_out;

    // ---- workspace layout (all 16B aligned) ----
    unsigned short* Whi = (unsigned short*)d_ws;          // 1,572,864 shorts
    unsigned short* Wlo = Whi + W_ELEMS;                  // 1,572,864 shorts
    float* bpk = (float*)(Wlo + W_ELEMS);                 // 2048 floats
    unsigned int* hpk = (unsigned int*)(bpk + NG);        // [2][BH] packed h

    repack_frag<<<W_ELEMS / 256, 256, 0, stream>>>(Wf, Wi, Wc, Wo, Whi, Wlo);
    pack_bias<<<NG / 256, 256, 0, stream>>>(bf, bi, bc, bo, bpk);
    init_h<<<2 * BH / 256, 256, 0, stream>>>(hpk);
    lstm_persist<<<NWG, 256, 0, stream>>>(x, Whi, Wlo, bpk, out, hpk);
}